// Round 1
// baseline (68.579 us; speedup 1.0000x reference)
//
#include <hip/hip_runtime.h>

#define B_DIM 8
#define N_DIM 512
#define NPAIR (B_DIM * N_DIM * N_DIM)   // 2,097,152

// Constants (double-precision derived, see derivation in session notes)
#define C0     0.28209479177387814f   // sqrt(1/(4pi))
#define C1     0.4886025119029199f    // sqrt(3/(4pi))
#define KXY    0.34549414947133544f   // C1 / sqrt(2)
#define SCALE2 3.2360432f             // sqrt(4pi*5/9) / cg(1,0,1,0,2,0) = sqrt(10pi/3)
#define SCALE3 3.1263148f             // sqrt(4pi*7/15) / cg(1,0,2,0,3,0) = sqrt(28pi/9)

__device__ __forceinline__ void cmul(float ar, float ai, float br, float bi,
                                     float& cr, float& ci) {
    cr = ar * br - ai * bi;
    ci = ar * bi + ai * br;
}

__global__ __launch_bounds__(256) void sph_pairs_kernel(
    const float* __restrict__ pos1,
    const float* __restrict__ pos2,
    float* __restrict__ out)
{
    const int p = blockIdx.x * blockDim.x + threadIdx.x;
    if (p >= NPAIR) return;

    const int j = p & (N_DIM - 1);
    const int i = (p >> 9) & (N_DIM - 1);
    const int b = p >> 18;

    const float* a1 = pos1 + (size_t)(b * N_DIM + i) * 3;
    const float* a2 = pos2 + (size_t)(b * N_DIM + j) * 3;

    const float rx = a1[0] - a2[0];
    const float ry = a1[1] - a2[1];
    const float rz = a1[2] - a2[2];
    const float r2 = rx * rx + ry * ry + rz * rz;
    const float norm = sqrtf(r2);
    const float rn = (r2 > 0.0f) ? rsqrtf(r2) : 0.0f;  // matches where(n>0, 1/n, 0)

    const float x = rx * rn;
    const float y = ry * rn;
    const float z = rz * rn;

    // l=1 complex components (include sqrt(3/4pi) factor), m1 = -1, 0, +1
    float br_[3], bi_[3];
    br_[0] =  KXY * x;  bi_[0] = -KXY * y;   // pm
    br_[1] =  C1  * z;  bi_[1] = 0.0f;       // p0
    br_[2] = -KXY * x;  bi_[2] = -KXY * y;   // pp

    // l=2 recurrence: new[mi] = scale2 * sum_m1i W2[m1i][mi] * b[m1i]*prev[mi-m1i]
    const float W2[3][5] = {
        {1.0f,        0.70710678f, 0.40824829f, 0.0f,        0.0f},
        {0.0f,        0.70710678f, 0.81649658f, 0.70710678f, 0.0f},
        {0.0f,        0.0f,        0.40824829f, 0.70710678f, 1.0f}};
    float q2r[5], q2i[5];
#pragma unroll
    for (int mi = 0; mi < 5; ++mi) {
        float sr = 0.0f, si = 0.0f;
#pragma unroll
        for (int m1i = 0; m1i < 3; ++m1i) {
            const int pidx = mi - m1i;
            if (pidx < 0 || pidx > 2) continue;
            const float w = W2[m1i][mi];
            if (w == 0.0f) continue;
            float cr, ci;
            cmul(br_[m1i], bi_[m1i], br_[pidx], bi_[pidx], cr, ci);
            sr += w * cr; si += w * ci;
        }
        q2r[mi] = sr * SCALE2;
        q2i[mi] = si * SCALE2;
    }

    // l=3 recurrence over prev = q2
    const float W3[3][7] = {
        {1.0f,        0.81649658f, 0.63245553f, 0.44721360f, 0.25819889f, 0.0f,        0.0f},
        {0.0f,        0.57735027f, 0.73029674f, 0.77459667f, 0.73029674f, 0.57735027f, 0.0f},
        {0.0f,        0.0f,        0.25819889f, 0.44721360f, 0.63245553f, 0.81649658f, 1.0f}};
    float q3r[7], q3i[7];
#pragma unroll
    for (int mi = 0; mi < 7; ++mi) {
        float sr = 0.0f, si = 0.0f;
#pragma unroll
        for (int m1i = 0; m1i < 3; ++m1i) {
            const int pidx = mi - m1i;
            if (pidx < 0 || pidx > 4) continue;
            const float w = W3[m1i][mi];
            if (w == 0.0f) continue;
            float cr, ci;
            cmul(br_[m1i], bi_[m1i], q2r[pidx], q2i[pidx], cr, ci);
            sr += w * cr; si += w * ci;
        }
        q3r[mi] = sr * SCALE3;
        q3i[mi] = si * SCALE3;
    }

    // ---- stores (all float2, 8B-aligned; consecutive threads -> contiguous) ----
    float* o0 = out;                       // psi0: 2 floats / pair
    float* o1 = out + (size_t)2  * NPAIR;  // psi1: 6 floats / pair
    float* o2 = out + (size_t)8  * NPAIR;  // psi2: 10 floats / pair
    float* o3 = out + (size_t)18 * NPAIR;  // psi3: 14 floats / pair
    float* o4 = out + (size_t)32 * NPAIR;  // norms: 1 float / pair

    ((float2*)o0)[p] = make_float2(C0, 0.0f);

    float2* w1 = (float2*)(o1 + (size_t)p * 6);
    w1[0] = make_float2(br_[0], bi_[0]);
    w1[1] = make_float2(br_[1], bi_[1]);
    w1[2] = make_float2(br_[2], bi_[2]);

    float2* w2 = (float2*)(o2 + (size_t)p * 10);
#pragma unroll
    for (int mi = 0; mi < 5; ++mi) w2[mi] = make_float2(q2r[mi], q2i[mi]);

    float2* w3 = (float2*)(o3 + (size_t)p * 14);
#pragma unroll
    for (int mi = 0; mi < 7; ++mi) w3[mi] = make_float2(q3r[mi], q3i[mi]);

    o4[p] = norm;
}

extern "C" void kernel_launch(void* const* d_in, const int* in_sizes, int n_in,
                              void* d_out, int out_size, void* d_ws, size_t ws_size,
                              hipStream_t stream) {
    (void)in_sizes; (void)n_in; (void)d_ws; (void)ws_size; (void)out_size;
    const float* pos1 = (const float*)d_in[0];
    const float* pos2 = (const float*)d_in[1];
    float* out = (float*)d_out;

    const int threads = 256;
    const int blocks = (NPAIR + threads - 1) / threads;  // 8192
    sph_pairs_kernel<<<blocks, threads, 0, stream>>>(pos1, pos2, out);
}